// Round 1
// baseline (1329.580 us; speedup 1.0000x reference)
//
#include <hip/hip_runtime.h>

#define NB 32
#define NC 256
#define NH 128
#define NW 128
#define NR 128
#define NF 256
#define HP 126
#define WP 126
#define HWSZ (NH*NW)

typedef __bf16 bf16;
typedef __bf16 bf16x8 __attribute__((ext_vector_type(8)));
typedef float  f32x4  __attribute__((ext_vector_type(4)));

// ---------------------------------------------------------------------------
// Kernel 1: channel mix  y[b,r,h,w] = sum_c f3[c,r] * x[b,c,h,w]   (y bf16)
// One block per (b,h): GEMM  A(128r x 256c) * B(256c x 128w).
// Both operands transposed into LDS as [row][k] with k contiguous.
// ---------------------------------------------------------------------------
__global__ __launch_bounds__(256) void k1_chanmix(
    const float* __restrict__ x, const float* __restrict__ f3,
    bf16* __restrict__ y)
{
    __shared__ __align__(16) bf16 As[128*72];   // A[r][kk], kk = c-c0, pad 72
    __shared__ __align__(16) bf16 Bs[128*72];   // B^T[w][kk]

    const int t    = threadIdx.x;
    const int b    = blockIdx.x >> 7;
    const int h    = blockIdx.x & 127;
    const int lane = t & 63;
    const int wv   = t >> 6;
    const int lrow = lane & 15;
    const int quad = lane >> 4;
    const int m0   = wv * 32;   // each wave: 32 rows of r, all 128 w

    const float* xrow = x + (size_t)b*NC*HWSZ + (size_t)h*NW;

    f32x4 acc[2][8];
#pragma unroll
    for (int mi=0; mi<2; ++mi)
#pragma unroll
        for (int ni=0; ni<8; ++ni) acc[mi][ni] = (f32x4){0.f,0.f,0.f,0.f};

    for (int c0=0; c0<NC; c0+=64) {
        // stage 64 k-rows of A (f3^T) and B (x row) into LDS, transposed
#pragma unroll
        for (int i=0;i<8;++i) {
            int idx = i*256 + t;          // 0..2047
            int kk  = idx >> 5;           // 0..63
            int j   = (idx & 31) * 4;     // 0..124
            float4 av = *(const float4*)(f3 + (size_t)(c0+kk)*NR + j);
            As[(j+0)*72+kk] = (bf16)av.x;
            As[(j+1)*72+kk] = (bf16)av.y;
            As[(j+2)*72+kk] = (bf16)av.z;
            As[(j+3)*72+kk] = (bf16)av.w;
            float4 bv = *(const float4*)(xrow + (size_t)(c0+kk)*HWSZ + j);
            Bs[(j+0)*72+kk] = (bf16)bv.x;
            Bs[(j+1)*72+kk] = (bf16)bv.y;
            Bs[(j+2)*72+kk] = (bf16)bv.z;
            Bs[(j+3)*72+kk] = (bf16)bv.w;
        }
        __syncthreads();
#pragma unroll
        for (int ks=0; ks<64; ks+=32) {
            const int col = ks + quad*8;
            bf16x8 af[2], bq[8];
#pragma unroll
            for (int mi=0; mi<2; ++mi)
                af[mi] = *(const bf16x8*)(As + (size_t)(m0 + mi*16 + lrow)*72 + col);
#pragma unroll
            for (int ni=0; ni<8; ++ni)
                bq[ni] = *(const bf16x8*)(Bs + (size_t)(ni*16 + lrow)*72 + col);
#pragma unroll
            for (int mi=0; mi<2; ++mi)
#pragma unroll
                for (int ni=0; ni<8; ++ni)
                    acc[mi][ni] = __builtin_amdgcn_mfma_f32_16x16x32_bf16(
                        af[mi], bq[ni], acc[mi][ni], 0, 0, 0);
        }
        __syncthreads();
    }

    // epilogue: C/D layout col=lane&15, row=quad*4+reg
    bf16* yrow = y + (size_t)b*NR*HWSZ + (size_t)h*NW;
#pragma unroll
    for (int mi=0; mi<2; ++mi)
#pragma unroll
        for (int ni=0; ni<8; ++ni) {
            int w = ni*16 + lrow;
#pragma unroll
            for (int reg=0; reg<4; ++reg) {
                int r = m0 + mi*16 + quad*4 + reg;
                yrow[(size_t)r*HWSZ + w] = (bf16)acc[mi][ni][reg];
            }
        }
}

// ---------------------------------------------------------------------------
// Kernel 2: depthwise 3x3 separable (fused into B staging) + output GEMM
//   z[r,w'] = sum_a f1[a,r] * sum_c f2[c,r] * y[b,r,hp+a,w'+c]
//   out[b,f,hp,w'] = sum_r f0[f,r] * z[r,w']
// One block per (hp, b): GEMM A(256f x 128r) * Z(128r x 126w').
// ---------------------------------------------------------------------------
__global__ __launch_bounds__(256) void k2_conv_gemm(
    const bf16* __restrict__ y, const float* __restrict__ f0,
    const float* __restrict__ f1, const float* __restrict__ f2,
    float* __restrict__ out)
{
    __shared__ __align__(16) bf16 Zs[128*136];   // Z^T[w'][r], pad 136
    __shared__ __align__(16) bf16 Afs[256*40];   // A[f][kk], kk = r-k0, pad 40

    const int t    = threadIdx.x;
    const int hp   = blockIdx.x;
    const int b    = blockIdx.y;
    const int lane = t & 63;
    const int wv   = t >> 6;
    const int lrow = lane & 15;
    const int quad = lane >> 4;
    const int m0   = wv * 64;   // each wave: 64 rows of f, all 128 w'

    // ---- phase 1: build Z^T in LDS ----
    const int wq    = t & 127;
    const int rbase = t >> 7;
    const bf16* yb = y + (size_t)b*NR*HWSZ + (size_t)hp*NW + wq;
    for (int i=0;i<64;++i) {
        int r = i*2 + rbase;
        float z = 0.f;
        if (wq < WP) {
            const bf16* yp = yb + (size_t)r*HWSZ;
            float f2v0 = f2[0*NR+r], f2v1 = f2[1*NR+r], f2v2 = f2[2*NR+r];
#pragma unroll
            for (int a=0;a<3;++a) {
                float s = f2v0*(float)yp[a*NW+0]
                        + f2v1*(float)yp[a*NW+1]
                        + f2v2*(float)yp[a*NW+2];
                z += f1[a*NR+r]*s;
            }
        }
        Zs[wq*136 + r] = (bf16)z;
    }
    __syncthreads();

    // ---- phase 2: GEMM over K=128 in chunks of 32 ----
    f32x4 acc[4][8];
#pragma unroll
    for (int mi=0; mi<4; ++mi)
#pragma unroll
        for (int ni=0; ni<8; ++ni) acc[mi][ni] = (f32x4){0.f,0.f,0.f,0.f};

    for (int k0=0; k0<NR; k0+=32) {
#pragma unroll
        for (int i=0;i<8;++i) {
            int idx = i*256 + t;          // 0..2047
            int f   = idx >> 3;           // 0..255
            int kk  = (idx & 7)*4;        // 0..28
            float4 v = *(const float4*)(f0 + (size_t)f*NR + k0 + kk);
            Afs[f*40+kk+0] = (bf16)v.x;
            Afs[f*40+kk+1] = (bf16)v.y;
            Afs[f*40+kk+2] = (bf16)v.z;
            Afs[f*40+kk+3] = (bf16)v.w;
        }
        __syncthreads();
        const int col = quad*8;
        bf16x8 af[4], bq[8];
#pragma unroll
        for (int mi=0; mi<4; ++mi)
            af[mi] = *(const bf16x8*)(Afs + (size_t)(m0 + mi*16 + lrow)*40 + col);
#pragma unroll
        for (int ni=0; ni<8; ++ni)
            bq[ni] = *(const bf16x8*)(Zs + (size_t)(ni*16 + lrow)*136 + k0 + col);
#pragma unroll
        for (int mi=0; mi<4; ++mi)
#pragma unroll
            for (int ni=0; ni<8; ++ni)
                acc[mi][ni] = __builtin_amdgcn_mfma_f32_16x16x32_bf16(
                    af[mi], bq[ni], acc[mi][ni], 0, 0, 0);
        __syncthreads();
    }

    // ---- epilogue ----
    float* ob = out + (size_t)b*NF*HP*WP + (size_t)hp*WP;
#pragma unroll
    for (int mi=0; mi<4; ++mi)
#pragma unroll
        for (int ni=0; ni<8; ++ni) {
            int wp = ni*16 + lrow;
            if (wp < WP) {
#pragma unroll
                for (int reg=0; reg<4; ++reg) {
                    int f = m0 + mi*16 + quad*4 + reg;
                    ob[(size_t)f*HP*WP + wp] = acc[mi][ni][reg];
                }
            }
        }
}

extern "C" void kernel_launch(void* const* d_in, const int* in_sizes, int n_in,
                              void* d_out, int out_size, void* d_ws, size_t ws_size,
                              hipStream_t stream) {
    const float* x  = (const float*)d_in[0];
    const float* f0 = (const float*)d_in[1];
    const float* f1 = (const float*)d_in[2];
    const float* f2 = (const float*)d_in[3];
    const float* f3 = (const float*)d_in[4];
    float* out = (float*)d_out;
    bf16* y = (bf16*)d_ws;   // 32*128*128*128 bf16 = 134 MB

    hipLaunchKernelGGL(k1_chanmix, dim3(NB*NH), dim3(256), 0, stream, x, f3, y);
    hipLaunchKernelGGL(k2_conv_gemm, dim3(HP, NB), dim3(256), 0, stream,
                       y, f0, f1, f2, out);
}